// Round 3
// baseline (337.525 us; speedup 1.0000x reference)
//
#include <hip/hip_runtime.h>

#define N_NODES 50000
#define N_EDGES 800000
#define SCAN_BLOCKS 196          // ceil(50000/256)
#define WIN 6250                 // dst window per XCD group (50000/8)
#define PLANE 1600000            // 50000*32 elements per dim-plane

typedef __attribute__((ext_vector_type(8))) short short8;
typedef __attribute__((ext_vector_type(4))) float f32x4;
typedef unsigned short ushort_t;
typedef unsigned int uint_t;

// ---------------- helpers ----------------
__device__ inline ushort_t f2bf(float f) {
    union { float f; uint_t u; } v; v.f = f;
    uint_t u = v.u;
    u += 0x7fffu + ((u >> 16) & 1u);   // RNE
    return (ushort_t)(u >> 16);
}
__device__ inline float bflo(uint_t v) { return __uint_as_float(v << 16); }
__device__ inline float bfhi(uint_t v) { return __uint_as_float(v & 0xffff0000u); }
__device__ inline float bf2f(ushort_t v) { return __uint_as_float((uint_t)v << 16); }

#define ACC8(V) { a[0] += bflo((V).x); a[1] += bfhi((V).x); \
                  a[2] += bflo((V).y); a[3] += bfhi((V).y); \
                  a[4] += bflo((V).z); a[5] += bfhi((V).z); \
                  a[6] += bflo((V).w); a[7] += bfhi((V).w); }

// ---------------- CSR build: XCD-windowed counting sort ----------------
__global__ void count_edges_mp(const int* __restrict__ ei, int* __restrict__ cnt) {
    int g = blockIdx.x & 7;
    int nb = gridDim.x >> 3;
    int bi = blockIdx.x >> 3;
    int lo = g * WIN;
    for (int e = bi * 256 + threadIdx.x; e < N_EDGES; e += nb * 256) {
        int d = ei[N_EDGES + e];
        if ((unsigned)(d - lo) < WIN) atomicAdd(&cnt[d], 1);
    }
}

__global__ void fill_csr_mp(const int* __restrict__ ei, int* __restrict__ cursor,
                            int* __restrict__ csr_src) {
    int g = blockIdx.x & 7;
    int nb = gridDim.x >> 3;
    int bi = blockIdx.x >> 3;
    int lo = g * WIN;
    for (int e = bi * 256 + threadIdx.x; e < N_EDGES; e += nb * 256) {
        int d = ei[N_EDGES + e];
        if ((unsigned)(d - lo) < WIN) {
            int p = atomicAdd(&cursor[d], 1);
            csr_src[p] = ei[e];
        }
    }
}

__global__ void block_sums(const int* __restrict__ cnt, int* __restrict__ bsum) {
    int i = blockIdx.x * 256 + threadIdx.x;
    int v = (i < N_NODES) ? cnt[i] : 0;
    for (int off = 32; off; off >>= 1) v += __shfl_down(v, off, 64);
    __shared__ int s[4];
    if ((threadIdx.x & 63) == 0) s[threadIdx.x >> 6] = v;
    __syncthreads();
    if (threadIdx.x == 0) bsum[blockIdx.x] = s[0] + s[1] + s[2] + s[3];
}

__global__ void scan_bsums(const int* __restrict__ bsum, int* __restrict__ bprefix,
                           int* __restrict__ rowstart) {
    __shared__ int s[256];
    int t = threadIdx.x;
    int v = (t < SCAN_BLOCKS) ? bsum[t] : 0;
    s[t] = v;
    __syncthreads();
    for (int off = 1; off < 256; off <<= 1) {
        int add = (t >= off) ? s[t - off] : 0;
        __syncthreads();
        s[t] += add;
        __syncthreads();
    }
    bprefix[t] = s[t] - v;
    if (t == 0) rowstart[N_NODES] = N_EDGES;
}

__global__ void apply_scan(const int* __restrict__ cnt, const int* __restrict__ bprefix,
                           int* __restrict__ rowstart, int* __restrict__ cursor) {
    __shared__ int s[256];
    int t = threadIdx.x;
    int i = blockIdx.x * 256 + t;
    int v = (i < N_NODES) ? cnt[i] : 0;
    s[t] = v;
    __syncthreads();
    for (int off = 1; off < 256; off <<= 1) {
        int add = (t >= off) ? s[t - off] : 0;
        __syncthreads();
        s[t] += add;
        __syncthreads();
    }
    int excl = s[t] - v + bprefix[blockIdx.x];
    if (i < N_NODES) { rowstart[i] = excl; cursor[i] = excl; }
}

// ---------------- fp32 -> bf16, plane-major [4][50000][32] ----------------
__global__ void cvt_bf16_pl(const float* __restrict__ in, ushort_t* __restrict__ out) {
    int i = blockIdx.x * 256 + threadIdx.x;     // over 1.6M float4's
    if (i >= 1600000) return;
    int d0 = (i & 31) * 4;                      // dim within row
    int node = i >> 5;
    float4 v = ((const float4*)in)[i];
    ushort4 o;
    o.x = f2bf(v.x); o.y = f2bf(v.y); o.z = f2bf(v.z); o.w = f2bf(v.w);
    int p = d0 >> 5, dd = d0 & 31;
    *(ushort4*)(out + ((size_t)p * 50000 + node) * 32 + dd) = o;
}

// ---------------- fused weight pre-pack (all 3 layers, 1 launch) ----------------
// elem (ks,t,lane,j) -> offset ((ks*8+t)*64+lane)*8+j ; B[n][k]: n=t*16+(lane&15),
// k=ks*32+(lane>>4)*8+j.
__global__ void pack_all(const float* __restrict__ Wl0, const float* __restrict__ Wr0,
                         const float* __restrict__ Wl1, const float* __restrict__ Wr1,
                         const float* __restrict__ Wl2, const float* __restrict__ Wr2,
                         ushort_t* __restrict__ pk0, ushort_t* __restrict__ pk1,
                         ushort_t* __restrict__ pkz) {
    int gi = blockIdx.x * 256 + threadIdx.x;    // 81920 total
    const float* Wl; const float* Wr; ushort_t* dst; int idx; bool zr = false;
    if (gi < 32768)       { Wl = Wl0; Wr = Wr0; dst = pk0; idx = gi; }
    else if (gi < 65536)  { Wl = Wl1; Wr = Wr1; dst = pk1; idx = gi - 32768; }
    else if (gi < 81920)  { Wl = Wl2; Wr = Wr2; dst = pkz; idx = gi - 65536; zr = true; }
    else return;
    int j = idx & 7, l = (idx >> 3) & 63, t = (idx >> 9) & 7, ks = idx >> 12;
    int n = t * 16 + (l & 15);
    int k = ks * 32 + (l >> 4) * 8 + j;
    float w;
    if (zr) w = (n < 64) ? Wl[k * 64 + n] : Wr[k * 64 + (n - 64)];
    else    w = (k < 128) ? Wl[k * 128 + n] : Wr[(k - 128) * 128 + n];
    dst[idx] = f2bf(w);
}

// ---------------- XCD-local dim-sliced mean aggregation ----------------
// role = blockIdx&7 -> XCD (round-robin dispatch heuristic; correctness-independent).
// slice s = role>>1 owns dim-plane s (3.2 MB, L2-resident); half = role&1 owns
// half the dst nodes. Per-XCD L2 fill = 3.2MB plane + nontemporal csr/mean.
// Wave: 4 nodes x 16 lanes; each lane owns 2 dims (one dword of the 64B slice row).
__global__ __launch_bounds__(256) void agg_pl(
    const ushort_t* __restrict__ feat_pl,       // [4][50000][32]
    const int* __restrict__ rowstart,
    const int* __restrict__ csr_src,
    ushort_t* __restrict__ mean_pl) {
    int role = blockIdx.x & 7;
    int wi   = blockIdx.x >> 3;
    int s    = role >> 1, half = role & 1;
    int lane = threadIdx.x & 63, wave = threadIdx.x >> 6;
    int sub = lane >> 4, sl = lane & 15, gb = sub << 4;
    const uint_t* pbase = (const uint_t*)feat_pl + (size_t)s * (PLANE / 2);  // 16 uints/row
    uint_t* mbase = (uint_t*)mean_pl + (size_t)s * (PLANE / 2);
    int nodeBase = half * 25000 + wi * 64 + wave * 16;
    int nodeLim  = (half + 1) * 25000;

    for (int p = 0; p < 4; ++p) {
        int node = nodeBase + p * 4 + sub;
        bool nv = node < nodeLim;
        int s0 = 0, s1 = 0;
        if (nv) { s0 = rowstart[node]; s1 = rowstart[node + 1]; }
        float a0 = 0.f, a1 = 0.f;

        int pos = s0;
        while (__any(pos < s1)) {
            int m = min(16, s1 - pos);           // per-sub, may be <=0
            int idxr = (sl < m) ? __builtin_nontemporal_load(&csr_src[pos + sl]) : 0;
            int mm = max(m, 0);
            mm = max(mm, __shfl_xor(mm, 16, 64));
            mm = max(mm, __shfl_xor(mm, 32, 64));
            for (int j = 0; j < mm; j += 8) {
                int  sidx[8];
                bool vld[8];
                #pragma unroll
                for (int k = 0; k < 8; ++k) {
                    int q = __shfl(idxr, (gb + j + k) & 63, 64);
                    vld[k]  = (j + k < m);
                    sidx[k] = vld[k] ? q : 0;
                }
                uint_t V[8];
                #pragma unroll
                for (int k = 0; k < 8; ++k)
                    V[k] = pbase[(size_t)sidx[k] * 16 + sl];
                #pragma unroll
                for (int k = 0; k < 8; ++k)
                    if (vld[k]) { a0 += bflo(V[k]); a1 += bfhi(V[k]); }
            }
            pos += 16;
        }
        if (nv) {
            float inv = 1.0f / fmaxf((float)(s1 - s0), 1.0f);
            uint_t packed = (uint_t)f2bf(a0 * inv) | ((uint_t)f2bf(a1 * inv) << 16);
            __builtin_nontemporal_store(packed, &mbase[(size_t)node * 16 + sl]);
        }
    }
}

// ---------------- MFMA GEMM, plane in/out, B staged in LDS ----------------
// h = relu([mean|root] @ [Wl;Wr] + b), all tensors plane-major [4][50000][32].
__global__ __launch_bounds__(256) void gemm_pl(
    const ushort_t* __restrict__ mean_pl, const ushort_t* __restrict__ root_pl,
    const ushort_t* __restrict__ Bpk, const float* __restrict__ bias,
    ushort_t* __restrict__ out_pl) {
    __shared__ ushort_t bsh[32768];             // 64 KB B-pack
    {
        const uint4* src = (const uint4*)Bpk;
        uint4* dst = (uint4*)bsh;
        for (int i = threadIdx.x; i < 4096; i += 256) dst[i] = src[i];
    }
    __syncthreads();

    int lane = threadIdx.x & 63;
    int wave = threadIdx.x >> 6;
    int row16 = lane & 15;
    int quad = lane >> 4;
    int rowBase = blockIdx.x * 64 + wave * 16;
    int arow = min(rowBase + row16, N_NODES - 1);
    const short8* bp = (const short8*)bsh + lane;

    f32x4 acc[8];
    #pragma unroll
    for (int t = 0; t < 8; ++t) { f32x4 z = {0.f, 0.f, 0.f, 0.f}; acc[t] = z; }

    #pragma unroll
    for (int ks = 0; ks < 8; ++ks) {
        const ushort_t* ab = (ks < 4)
            ? (mean_pl + ((size_t)ks * 50000 + arow) * 32 + quad * 8)
            : (root_pl + ((size_t)(ks - 4) * 50000 + arow) * 32 + quad * 8);
        short8 afrag = *(const short8*)ab;
        #pragma unroll
        for (int t = 0; t < 8; ++t) {
            short8 bfrag = bp[(ks * 8 + t) * 64];
            acc[t] = __builtin_amdgcn_mfma_f32_16x16x32_bf16(afrag, bfrag, acc[t], 0, 0, 0);
        }
    }

    #pragma unroll
    for (int t = 0; t < 8; ++t) {
        int col = t * 16 + row16;
        float bv = bias[col];
        int pl = col >> 5, dd = col & 31;
        #pragma unroll
        for (int r = 0; r < 4; ++r) {
            int row = rowBase + quad * 4 + r;
            if (row < N_NODES) {
                float v = fmaxf(acc[t][r] + bv, 0.f);
                out_pl[((size_t)pl * 50000 + row) * 32 + dd] = f2bf(v);
            }
        }
    }
}

// ---------------- layer-2 pre-transform: [z | r] = h @ [Wl2 | Wr2], r += b2 ----------------
__global__ __launch_bounds__(256) void gemm_zr_pl(
    const ushort_t* __restrict__ h_pl, const ushort_t* __restrict__ Bpk,
    const float* __restrict__ bias,
    ushort_t* __restrict__ z_bf, float* __restrict__ r_f32) {
    __shared__ ushort_t bsh[16384];             // 32 KB B-pack
    {
        const uint4* src = (const uint4*)Bpk;
        uint4* dst = (uint4*)bsh;
        for (int i = threadIdx.x; i < 2048; i += 256) dst[i] = src[i];
    }
    __syncthreads();

    int lane = threadIdx.x & 63;
    int wave = threadIdx.x >> 6;
    int row16 = lane & 15;
    int quad = lane >> 4;
    int rowBase = blockIdx.x * 64 + wave * 16;
    int arow = min(rowBase + row16, N_NODES - 1);
    const short8* bp = (const short8*)bsh + lane;

    f32x4 acc[8];
    #pragma unroll
    for (int t = 0; t < 8; ++t) { f32x4 z = {0.f, 0.f, 0.f, 0.f}; acc[t] = z; }

    #pragma unroll
    for (int ks = 0; ks < 4; ++ks) {
        short8 afrag = *(const short8*)(h_pl + ((size_t)ks * 50000 + arow) * 32 + quad * 8);
        #pragma unroll
        for (int t = 0; t < 8; ++t) {
            short8 bfrag = bp[(ks * 8 + t) * 64];
            acc[t] = __builtin_amdgcn_mfma_f32_16x16x32_bf16(afrag, bfrag, acc[t], 0, 0, 0);
        }
    }

    #pragma unroll
    for (int t = 0; t < 8; ++t) {
        int col = t * 16 + row16;
        #pragma unroll
        for (int r = 0; r < 4; ++r) {
            int row = rowBase + quad * 4 + r;
            if (row < N_NODES) {
                if (col < 64) {
                    z_bf[(size_t)row * 64 + col] = f2bf(acc[t][r]);
                } else {
                    r_f32[(size_t)row * 64 + (col - 64)] = acc[t][r] + bias[col - 64];
                }
            }
        }
    }
}

// ---------------- final: mean(z[src]) + r, log_softmax (wide gather: 8 rows/instr) ----------------
__global__ __launch_bounds__(256) void final_agg_softmax2(
    const ushort_t* __restrict__ z_bf, const float* __restrict__ r_f32,
    const int* __restrict__ rowstart, const int* __restrict__ csr_src,
    float* __restrict__ out) {
    int lane = threadIdx.x & 63;
    int wave = threadIdx.x >> 6;
    int sub = lane >> 3;                  // node slot 0..7
    int sl  = lane & 7;                   // lane within node row
    int gb  = sub << 3;
    int node = blockIdx.x * 32 + wave * 8 + sub;
    int s0 = 0, s1 = 0;
    if (node < N_NODES) { s0 = rowstart[node]; s1 = rowstart[node + 1]; }

    float a[8];
    #pragma unroll
    for (int k = 0; k < 8; ++k) a[k] = 0.f;
    const uint_t* zb = (const uint_t*)z_bf;

    int pos = s0;
    while (__any(pos < s1)) {
        int m = min(8, s1 - pos);
        int idxr = (sl < m) ? csr_src[pos + sl] : 0;
        int  sidx[8];
        bool vld[8];
        #pragma unroll
        for (int k = 0; k < 8; ++k) {
            int q = __shfl(idxr, (gb + k) & 63, 64);
            vld[k]  = (k < m);
            sidx[k] = vld[k] ? q : 0;
        }
        uint4 V[8];
        #pragma unroll
        for (int k = 0; k < 8; ++k)
            V[k] = *(const uint4*)(zb + (size_t)sidx[k] * 32 + (sl << 2));
        #pragma unroll
        for (int k = 0; k < 8; ++k)
            if (vld[k]) { ACC8(V[k]); }
        pos += 8;
    }
    if (node >= N_NODES) return;

    float inv = 1.0f / fmaxf((float)(s1 - s0), 1.0f);
    const float4* rr = (const float4*)(r_f32 + (size_t)node * 64 + sl * 8);
    float4 rA = rr[0], rB = rr[1];
    float h[8];
    h[0] = a[0] * inv + rA.x; h[1] = a[1] * inv + rA.y;
    h[2] = a[2] * inv + rA.z; h[3] = a[3] * inv + rA.w;
    h[4] = a[4] * inv + rB.x; h[5] = a[5] * inv + rB.y;
    h[6] = a[6] * inv + rB.z; h[7] = a[7] * inv + rB.w;

    float mx = fmaxf(fmaxf(fmaxf(h[0], h[1]), fmaxf(h[2], h[3])),
                     fmaxf(fmaxf(h[4], h[5]), fmaxf(h[6], h[7])));
    mx = fmaxf(mx, __shfl_xor(mx, 1, 64));
    mx = fmaxf(mx, __shfl_xor(mx, 2, 64));
    mx = fmaxf(mx, __shfl_xor(mx, 4, 64));
    float s = 0.f;
    #pragma unroll
    for (int k = 0; k < 8; ++k) s += expf(h[k] - mx);
    s += __shfl_xor(s, 1, 64);
    s += __shfl_xor(s, 2, 64);
    s += __shfl_xor(s, 4, 64);
    float lse = mx + logf(s);

    size_t o1 = (size_t)node * 64 + sl * 8;
    size_t o2 = (size_t)N_NODES * 64 + o1;
    *(float4*)(out + o1)     = make_float4(h[0] - lse, h[1] - lse, h[2] - lse, h[3] - lse);
    *(float4*)(out + o1 + 4) = make_float4(h[4] - lse, h[5] - lse, h[6] - lse, h[7] - lse);
    *(float4*)(out + o2)     = make_float4(h[0], h[1], h[2], h[3]);
    *(float4*)(out + o2 + 4) = make_float4(h[4], h[5], h[6], h[7]);
}

extern "C" void kernel_launch(void* const* d_in, const int* in_sizes, int n_in,
                              void* d_out, int out_size, void* d_ws, size_t ws_size,
                              hipStream_t stream) {
    const float* x  = (const float*)d_in[0];
    const int* ei   = (const int*)d_in[1];
    const float* Wl0 = (const float*)d_in[2];
    const float* Wr0 = (const float*)d_in[3];
    const float* b0  = (const float*)d_in[4];
    const float* Wl1 = (const float*)d_in[5];
    const float* Wr1 = (const float*)d_in[6];
    const float* b1  = (const float*)d_in[7];
    const float* Wl2 = (const float*)d_in[8];
    const float* Wr2 = (const float*)d_in[9];
    const float* b2  = (const float*)d_in[10];
    float* out = (float*)d_out;

    char* ws = (char*)d_ws;
    int* cnt      = (int*)(ws + 0x000000);
    int* rowstart = (int*)(ws + 0x040000);
    int* cursor   = (int*)(ws + 0x080000);
    int* bsum     = (int*)(ws + 0x0C0000);
    int* bprefix  = (int*)(ws + 0x0C1000);
    int* csr_src  = (int*)(ws + 0x100000);            // 3.2 MB
    ushort_t* pk0 = (ushort_t*)(ws + 0x420000);       // 64 KB
    ushort_t* pk1 = (ushort_t*)(ws + 0x440000);       // 64 KB
    ushort_t* pkz = (ushort_t*)(ws + 0x460000);       // 32 KB
    ushort_t* x_pl    = (ushort_t*)(ws + 0x0500000);  // 12.8 MB  [4][50000][32]
    ushort_t* mean_pl = (ushort_t*)(ws + 0x1200000);  // 12.8 MB
    ushort_t* h_pl    = (ushort_t*)(ws + 0x1F00000);  // 12.8 MB
    ushort_t* h2_pl   = (ushort_t*)(ws + 0x2C00000);  // 12.8 MB
    ushort_t* z_bf    = (ushort_t*)(ws + 0x3900000);  // 6.4 MB  [50000][64]
    float*    r_f32   = (float*)  (ws + 0x4000000);   // 12.8 MB

    // ---- weight pre-pack (single launch; overlaps CSR build) ----
    pack_all<<<320, 256, 0, stream>>>(Wl0, Wr0, Wl1, Wr1, Wl2, Wr2, pk0, pk1, pkz);

    // ---- CSR build (XCD-windowed counting sort) ----
    hipMemsetAsync(cnt, 0, N_NODES * sizeof(int), stream);
    count_edges_mp<<<1024, 256, 0, stream>>>(ei, cnt);
    block_sums<<<SCAN_BLOCKS, 256, 0, stream>>>(cnt, bsum);
    scan_bsums<<<1, 256, 0, stream>>>(bsum, bprefix, rowstart);
    apply_scan<<<SCAN_BLOCKS, 256, 0, stream>>>(cnt, bprefix, rowstart, cursor);
    fill_csr_mp<<<1024, 256, 0, stream>>>(ei, cursor, csr_src);

    // ---- x -> bf16 planes ----
    cvt_bf16_pl<<<6250, 256, 0, stream>>>(x, x_pl);

    // ---- layer 0 ----
    agg_pl<<<3128, 256, 0, stream>>>(x_pl, rowstart, csr_src, mean_pl);
    gemm_pl<<<782, 256, 0, stream>>>(mean_pl, x_pl, pk0, b0, h_pl);

    // ---- layer 1 ----
    agg_pl<<<3128, 256, 0, stream>>>(h_pl, rowstart, csr_src, mean_pl);
    gemm_pl<<<782, 256, 0, stream>>>(mean_pl, h_pl, pk1, b1, h2_pl);

    // ---- layer 2: transform-first, then fused agg+softmax ----
    gemm_zr_pl<<<782, 256, 0, stream>>>(h2_pl, pkz, b2, z_bf, r_f32);
    final_agg_softmax2<<<1563, 256, 0, stream>>>(z_bf, r_f32, rowstart, csr_src, out);
}